// Round 1
// baseline (474.829 us; speedup 1.0000x reference)
//
#include <hip/hip_runtime.h>
#include <hip/hip_bf16.h>
#include <math.h>

#define N_NODES 50000
#define N_EDGES 800000
#define FDIM 128

// ---------------------------------------------------------------------------
// K1: GRU-evolve the weight matrix.
// gi = W0 @ W_ih^T + b_ih ; gh = W0 @ W_hh^T + b_hh   (shapes 128x384)
// r = sig(gi_r+gh_r); z = sig(gi_z+gh_z); n = tanh(gi_n + r*gh_n)
// W = (1-z)*n + z*W0
// One block per row i of W0; 384 threads = one per output column jj of gi/gh.
// ---------------------------------------------------------------------------
__global__ __launch_bounds__(384) void evolve_kernel(
    const float* __restrict__ W0, const float* __restrict__ Wih,
    const float* __restrict__ Whh, const float* __restrict__ bih,
    const float* __restrict__ bhh, float* __restrict__ W) {
  int i = blockIdx.x;       // 0..127
  int jj = threadIdx.x;     // 0..383
  __shared__ float w0s[FDIM];
  __shared__ float gis[3 * FDIM];
  __shared__ float ghs[3 * FDIM];
  if (jj < FDIM) w0s[jj] = W0[i * FDIM + jj];
  __syncthreads();
  float gi = bih[jj], gh = bhh[jj];
  const float4* wih4 = (const float4*)(Wih + jj * FDIM);
  const float4* whh4 = (const float4*)(Whh + jj * FDIM);
#pragma unroll 8
  for (int k = 0; k < FDIM / 4; k++) {
    float4 a = wih4[k];
    float4 b = whh4[k];
    float w0a = w0s[4 * k], w0b = w0s[4 * k + 1];
    float w0c = w0s[4 * k + 2], w0d = w0s[4 * k + 3];
    gi += a.x * w0a + a.y * w0b + a.z * w0c + a.w * w0d;
    gh += b.x * w0a + b.y * w0b + b.z * w0c + b.w * w0d;
  }
  gis[jj] = gi;
  ghs[jj] = gh;
  __syncthreads();
  if (jj < FDIM) {
    float r = 1.0f / (1.0f + expf(-(gis[jj] + ghs[jj])));
    float z = 1.0f / (1.0f + expf(-(gis[jj + FDIM] + ghs[jj + FDIM])));
    float nn = tanhf(gis[jj + 2 * FDIM] + r * ghs[jj + 2 * FDIM]);
    W[i * FDIM + jj] = (1.0f - z) * nn + z * w0s[jj];
  }
}

// ---------------------------------------------------------------------------
// K2: init deg = 1.0 (self-loop weight), cnt = 0
// ---------------------------------------------------------------------------
__global__ void init_deg_kernel(float* __restrict__ deg, int* __restrict__ cnt,
                                int n) {
  int i = blockIdx.x * blockDim.x + threadIdx.x;
  if (i < n) {
    deg[i] = 1.0f;   // self loop contributes weight 1
    cnt[i] = 0;
  }
}

// ---------------------------------------------------------------------------
// K3: histogram — weighted degree + incoming-edge count per dst
// ---------------------------------------------------------------------------
__global__ void hist_kernel(const int* __restrict__ ei,
                            const float* __restrict__ ew,
                            float* __restrict__ deg, int* __restrict__ cnt,
                            int e) {
  int idx = blockIdx.x * blockDim.x + threadIdx.x;
  if (idx < e) {
    int dst = ei[N_EDGES + idx];
    atomicAdd(&deg[dst], ew[idx]);
    atomicAdd(&cnt[dst], 1);
  }
}

// ---------------------------------------------------------------------------
// K4: dinv = rsqrt(deg) (deg >= 1 always, keep ref guard anyway)
// ---------------------------------------------------------------------------
__global__ void dinv_kernel(const float* __restrict__ deg,
                            float* __restrict__ dinv, int n) {
  int i = blockIdx.x * blockDim.x + threadIdx.x;
  if (i < n) {
    float d = deg[i];
    dinv[i] = (d > 0.0f) ? rsqrtf(d) : 0.0f;
  }
}

// ---------------------------------------------------------------------------
// K5: exclusive scan of cnt -> offs[0..n], also copy into cur (scatter cursor)
// single block of 1024, each thread owns a contiguous segment.
// ---------------------------------------------------------------------------
__global__ __launch_bounds__(1024) void scan_kernel(const int* __restrict__ cnt,
                                                    int* __restrict__ offs,
                                                    int* __restrict__ cur,
                                                    int n) {
  __shared__ int part[1024];
  int t = threadIdx.x;
  const int SEG = (N_NODES + 1023) / 1024;  // 49
  int base = t * SEG;
  int s = 0;
  for (int i = 0; i < SEG; i++) {
    int idx = base + i;
    if (idx < n) s += cnt[idx];
  }
  part[t] = s;
  __syncthreads();
  // Hillis-Steele inclusive scan
  for (int off = 1; off < 1024; off <<= 1) {
    int v = (t >= off) ? part[t - off] : 0;
    __syncthreads();
    part[t] += v;
    __syncthreads();
  }
  int run = (t == 0) ? 0 : part[t - 1];
  for (int i = 0; i < SEG; i++) {
    int idx = base + i;
    if (idx < n) {
      offs[idx] = run;
      cur[idx] = run;
      run += cnt[idx];
    }
  }
  if (t == 1023) offs[n] = part[1023];
}

// ---------------------------------------------------------------------------
// K6: scatter edges into CSR-by-dst; precompute norm = dinv[src]*w*dinv[dst]
// ---------------------------------------------------------------------------
__global__ void scatter_kernel(const int* __restrict__ ei,
                               const float* __restrict__ ew,
                               const float* __restrict__ dinv,
                               int* __restrict__ cur,
                               int* __restrict__ csr_src,
                               float* __restrict__ csr_w, int e) {
  int idx = blockIdx.x * blockDim.x + threadIdx.x;
  if (idx < e) {
    int src = ei[idx];
    int dst = ei[N_EDGES + idx];
    float nrm = dinv[src] * ew[idx] * dinv[dst];
    int pos = atomicAdd(&cur[dst], 1);
    csr_src[pos] = src;
    csr_w[pos] = nrm;
  }
}

// ---------------------------------------------------------------------------
// K7: xw = x @ W   (fp32, LDS-staged W; 16 rows per block pass)
// 256 threads: c4 = (t&31)*4 column group, slot = t>>5 -> rows 2*slot,2*slot+1
// n = 50000 = 16 * 3125, no tail.
// ---------------------------------------------------------------------------
__global__ __launch_bounds__(256) void xw_kernel(const float* __restrict__ x,
                                                 const float* __restrict__ W,
                                                 float* __restrict__ xw,
                                                 int n) {
  __shared__ float Ws[FDIM * FDIM];  // 64 KiB
  __shared__ float xs[16 * FDIM];    // 8 KiB
  int t = threadIdx.x;
  const float4* W4 = (const float4*)W;
  float4* Ws4 = (float4*)Ws;
#pragma unroll
  for (int i = 0; i < 16; i++) Ws4[i * 256 + t] = W4[i * 256 + t];
  int c4 = (t & 31) * 4;
  int slot = t >> 5;  // 0..7
  for (int rowBase = blockIdx.x * 16; rowBase < n; rowBase += gridDim.x * 16) {
    __syncthreads();  // Ws ready (iter 0) / xs no longer read (iter >0)
    float4* xs4 = (float4*)xs;
    const float4* xg = (const float4*)(x + (size_t)rowBase * FDIM);
    xs4[t] = xg[t];
    xs4[256 + t] = xg[256 + t];
    __syncthreads();
    float a0 = 0, a1 = 0, a2 = 0, a3 = 0;
    float b0 = 0, b1 = 0, b2 = 0, b3 = 0;
    const float* x0 = xs + (2 * slot) * FDIM;
    const float* x1 = x0 + FDIM;
#pragma unroll 4
    for (int k = 0; k < FDIM; k++) {
      float4 wv = *((const float4*)(Ws + k * FDIM + c4));
      float xa = x0[k], xb = x1[k];
      a0 += xa * wv.x; a1 += xa * wv.y; a2 += xa * wv.z; a3 += xa * wv.w;
      b0 += xb * wv.x; b1 += xb * wv.y; b2 += xb * wv.z; b3 += xb * wv.w;
    }
    float4* o0 = (float4*)(xw + (size_t)(rowBase + 2 * slot) * FDIM + c4);
    float4* o1 = (float4*)(xw + (size_t)(rowBase + 2 * slot + 1) * FDIM + c4);
    *o0 = make_float4(a0, a1, a2, a3);
    *o1 = make_float4(b0, b1, b2, b3);
  }
}

// ---------------------------------------------------------------------------
// K8: per-node gather + tanh + w_lin dot + bias (fused epilogue).
// One wave (64 lanes) per dst node; lane holds features 2*lane, 2*lane+1.
// ---------------------------------------------------------------------------
__global__ __launch_bounds__(256) void gather_kernel(
    const float* __restrict__ xw, const int* __restrict__ offs,
    const int* __restrict__ csr_src, const float* __restrict__ csr_w,
    const float* __restrict__ dinv, const float* __restrict__ wl,
    const float* __restrict__ bl, float* __restrict__ out, int n) {
  int wid = (int)((blockIdx.x * (size_t)blockDim.x + threadIdx.x) >> 6);
  int lane = threadIdx.x & 63;
  if (wid >= n) return;
  const float2* xw2 = (const float2*)xw;
  float di = dinv[wid];
  float2 v = xw2[(size_t)wid * 64 + lane];
  float sn = di * di;  // self-loop norm = dinv*1*dinv
  float ax = sn * v.x, ay = sn * v.y;
  int beg = offs[wid], end = offs[wid + 1];
  for (int e = beg; e < end; e++) {
    int s = csr_src[e];
    float wn = csr_w[e];
    float2 u = xw2[(size_t)s * 64 + lane];
    ax += wn * u.x;
    ay += wn * u.y;
  }
  float2 wv = ((const float2*)wl)[lane];
  float p = tanhf(ax) * wv.x + tanhf(ay) * wv.y;
#pragma unroll
  for (int o = 32; o > 0; o >>= 1) p += __shfl_down(p, o, 64);
  if (lane == 0) out[wid] = p + bl[0];
}

// ---------------------------------------------------------------------------
extern "C" void kernel_launch(void* const* d_in, const int* in_sizes, int n_in,
                              void* d_out, int out_size, void* d_ws,
                              size_t ws_size, hipStream_t stream) {
  const float* x = (const float*)d_in[0];     // (N,128)
  const int* ei = (const int*)d_in[1];        // (2,E)
  const float* ew = (const float*)d_in[2];    // (E,)
  const float* W0 = (const float*)d_in[3];    // (128,128)
  const float* Wih = (const float*)d_in[4];   // (384,128)
  const float* Whh = (const float*)d_in[5];   // (384,128)
  const float* bih = (const float*)d_in[6];   // (384,)
  const float* bhh = (const float*)d_in[7];   // (384,)
  const float* wl = (const float*)d_in[8];    // (1,128)
  const float* bl = (const float*)d_in[9];    // (1,)
  float* out = (float*)d_out;                 // (N,1)

  // Workspace layout (fp32 units, all 16B-aligned)
  float* ws = (float*)d_ws;
  float* W_ev = ws;                         // 16384
  float* xw = W_ev + 16384;                 // 6,400,000
  float* deg = xw + (size_t)N_NODES * FDIM; // 50000
  float* dinv = deg + N_NODES;              // 50000
  int* cnt = (int*)(dinv + N_NODES);        // 50000
  int* offs = cnt + N_NODES;                // 50004 (padded)
  int* cur = offs + 50004;                  // 50004 (padded)
  int* csr_src = cur + 50004;               // 800000
  float* csr_w = (float*)(csr_src + N_EDGES); // 800000

  // K1: evolve W
  evolve_kernel<<<FDIM, 384, 0, stream>>>(W0, Wih, Whh, bih, bhh, W_ev);
  // K2: init
  init_deg_kernel<<<(N_NODES + 255) / 256, 256, 0, stream>>>(deg, cnt, N_NODES);
  // K3: histogram
  hist_kernel<<<(N_EDGES + 255) / 256, 256, 0, stream>>>(ei, ew, deg, cnt,
                                                         N_EDGES);
  // K4: dinv
  dinv_kernel<<<(N_NODES + 255) / 256, 256, 0, stream>>>(deg, dinv, N_NODES);
  // K5: scan
  scan_kernel<<<1, 1024, 0, stream>>>(cnt, offs, cur, N_NODES);
  // K6: scatter to CSR
  scatter_kernel<<<(N_EDGES + 255) / 256, 256, 0, stream>>>(
      ei, ew, dinv, cur, csr_src, csr_w, N_EDGES);
  // K7: xw = x @ W_ev   (50000 = 16*3125 rows; 625 blocks * 5 passes)
  xw_kernel<<<625, 256, 0, stream>>>(x, W_ev, xw, N_NODES);
  // K8: fused gather + tanh + linear
  gather_kernel<<<(N_NODES * 64) / 256, 256, 0, stream>>>(
      xw, offs, csr_src, csr_w, dinv, wl, bl, out, N_NODES);
}

// Round 2
// 358.664 us; speedup vs baseline: 1.3239x; 1.3239x over previous
//
#include <hip/hip_runtime.h>
#include <hip/hip_bf16.h>
#include <math.h>

#define N_NODES 50000
#define N_EDGES 800000
#define FDIM 128
#define SCAN_BLOCKS 196  // ceil(50000/256)

// ---------------------------------------------------------------------------
// K1: GRU-evolve the weight matrix.
// ---------------------------------------------------------------------------
__global__ __launch_bounds__(384) void evolve_kernel(
    const float* __restrict__ W0, const float* __restrict__ Wih,
    const float* __restrict__ Whh, const float* __restrict__ bih,
    const float* __restrict__ bhh, float* __restrict__ W) {
  int i = blockIdx.x;       // 0..127
  int jj = threadIdx.x;     // 0..383
  __shared__ float w0s[FDIM];
  __shared__ float gis[3 * FDIM];
  __shared__ float ghs[3 * FDIM];
  if (jj < FDIM) w0s[jj] = W0[i * FDIM + jj];
  __syncthreads();
  float gi = bih[jj], gh = bhh[jj];
  const float4* wih4 = (const float4*)(Wih + jj * FDIM);
  const float4* whh4 = (const float4*)(Whh + jj * FDIM);
#pragma unroll 8
  for (int k = 0; k < FDIM / 4; k++) {
    float4 a = wih4[k];
    float4 b = whh4[k];
    float w0a = w0s[4 * k], w0b = w0s[4 * k + 1];
    float w0c = w0s[4 * k + 2], w0d = w0s[4 * k + 3];
    gi += a.x * w0a + a.y * w0b + a.z * w0c + a.w * w0d;
    gh += b.x * w0a + b.y * w0b + b.z * w0c + b.w * w0d;
  }
  gis[jj] = gi;
  ghs[jj] = gh;
  __syncthreads();
  if (jj < FDIM) {
    float r = 1.0f / (1.0f + expf(-(gis[jj] + ghs[jj])));
    float z = 1.0f / (1.0f + expf(-(gis[jj + FDIM] + ghs[jj + FDIM])));
    float nn = tanhf(gis[jj + 2 * FDIM] + r * ghs[jj + 2 * FDIM]);
    W[i * FDIM + jj] = (1.0f - z) * nn + z * w0s[jj];
  }
}

// ---------------------------------------------------------------------------
// K2: init deg = 1.0 (self-loop weight), cnt = 0
// ---------------------------------------------------------------------------
__global__ void init_deg_kernel(float* __restrict__ deg, int* __restrict__ cnt,
                                int n) {
  int i = blockIdx.x * blockDim.x + threadIdx.x;
  if (i < n) {
    deg[i] = 1.0f;
    cnt[i] = 0;
  }
}

// ---------------------------------------------------------------------------
// K3: histogram — weighted degree + incoming-edge count per dst
// ---------------------------------------------------------------------------
__global__ void hist_kernel(const int* __restrict__ ei,
                            const float* __restrict__ ew,
                            float* __restrict__ deg, int* __restrict__ cnt,
                            int e) {
  int idx = blockIdx.x * blockDim.x + threadIdx.x;
  if (idx < e) {
    int dst = ei[N_EDGES + idx];
    atomicAdd(&deg[dst], ew[idx]);
    atomicAdd(&cnt[dst], 1);
  }
}

// ---------------------------------------------------------------------------
// K5a: per-block partial sums of cnt (256 elems/block) + fused dinv compute.
// ---------------------------------------------------------------------------
__global__ __launch_bounds__(256) void partial_kernel(
    const int* __restrict__ cnt, const float* __restrict__ deg,
    float* __restrict__ dinv, int* __restrict__ part, int n) {
  int t = threadIdx.x;
  int idx = blockIdx.x * 256 + t;
  int v = (idx < n) ? cnt[idx] : 0;
  if (idx < n) {
    float d = deg[idx];
    dinv[idx] = (d > 0.0f) ? rsqrtf(d) : 0.0f;
  }
  int r = v;
#pragma unroll
  for (int o = 32; o > 0; o >>= 1) r += __shfl_down(r, o, 64);
  __shared__ int s[4];
  if ((t & 63) == 0) s[t >> 6] = r;
  __syncthreads();
  if (t == 0) part[blockIdx.x] = s[0] + s[1] + s[2] + s[3];
}

// ---------------------------------------------------------------------------
// K5b: exclusive scan of SCAN_BLOCKS partials (single small block).
// ---------------------------------------------------------------------------
__global__ __launch_bounds__(256) void scan_part_kernel(int* __restrict__ part) {
  __shared__ int tmp[256];
  int t = threadIdx.x;
  int v = (t < SCAN_BLOCKS) ? part[t] : 0;
  tmp[t] = v;
  __syncthreads();
#pragma unroll
  for (int off = 1; off < 256; off <<= 1) {
    int u = (t >= off) ? tmp[t - off] : 0;
    __syncthreads();
    tmp[t] += u;
    __syncthreads();
  }
  if (t < SCAN_BLOCKS) part[t] = tmp[t] - v;  // exclusive
}

// ---------------------------------------------------------------------------
// K5c: per-block local exclusive scan + partial offset -> offs, cur
// ---------------------------------------------------------------------------
__global__ __launch_bounds__(256) void scan_final_kernel(
    const int* __restrict__ cnt, const int* __restrict__ part,
    int* __restrict__ offs, int* __restrict__ cur, int n) {
  __shared__ int tmp[256];
  int t = threadIdx.x;
  int idx = blockIdx.x * 256 + t;
  int v = (idx < n) ? cnt[idx] : 0;
  tmp[t] = v;
  __syncthreads();
#pragma unroll
  for (int off = 1; off < 256; off <<= 1) {
    int u = (t >= off) ? tmp[t - off] : 0;
    __syncthreads();
    tmp[t] += u;
    __syncthreads();
  }
  int excl = part[blockIdx.x] + tmp[t] - v;
  if (idx < n) {
    offs[idx] = excl;
    cur[idx] = excl;
  }
  if (idx == n - 1) offs[n] = excl + v;
}

// ---------------------------------------------------------------------------
// K6: scatter edges into CSR-by-dst; precompute norm = dinv[src]*w*dinv[dst]
// ---------------------------------------------------------------------------
__global__ void scatter_kernel(const int* __restrict__ ei,
                               const float* __restrict__ ew,
                               const float* __restrict__ dinv,
                               int* __restrict__ cur,
                               int* __restrict__ csr_src,
                               float* __restrict__ csr_w, int e) {
  int idx = blockIdx.x * blockDim.x + threadIdx.x;
  if (idx < e) {
    int src = ei[idx];
    int dst = ei[N_EDGES + idx];
    float nrm = dinv[src] * ew[idx] * dinv[dst];
    int pos = atomicAdd(&cur[dst], 1);
    csr_src[pos] = src;
    csr_w[pos] = nrm;
  }
}

// ---------------------------------------------------------------------------
// K7: xw = x @ W   (fp32, LDS-staged W; 16 rows per block pass)
// ---------------------------------------------------------------------------
__global__ __launch_bounds__(256) void xw_kernel(const float* __restrict__ x,
                                                 const float* __restrict__ W,
                                                 float* __restrict__ xw,
                                                 int n) {
  __shared__ float Ws[FDIM * FDIM];  // 64 KiB
  __shared__ float xs[16 * FDIM];    // 8 KiB
  int t = threadIdx.x;
  const float4* W4 = (const float4*)W;
  float4* Ws4 = (float4*)Ws;
#pragma unroll
  for (int i = 0; i < 16; i++) Ws4[i * 256 + t] = W4[i * 256 + t];
  int c4 = (t & 31) * 4;
  int slot = t >> 5;  // 0..7
  for (int rowBase = blockIdx.x * 16; rowBase < n; rowBase += gridDim.x * 16) {
    __syncthreads();
    float4* xs4 = (float4*)xs;
    const float4* xg = (const float4*)(x + (size_t)rowBase * FDIM);
    xs4[t] = xg[t];
    xs4[256 + t] = xg[256 + t];
    __syncthreads();
    float a0 = 0, a1 = 0, a2 = 0, a3 = 0;
    float b0 = 0, b1 = 0, b2 = 0, b3 = 0;
    const float* x0 = xs + (2 * slot) * FDIM;
    const float* x1 = x0 + FDIM;
#pragma unroll 4
    for (int k = 0; k < FDIM; k++) {
      float4 wv = *((const float4*)(Ws + k * FDIM + c4));
      float xa = x0[k], xb = x1[k];
      a0 += xa * wv.x; a1 += xa * wv.y; a2 += xa * wv.z; a3 += xa * wv.w;
      b0 += xb * wv.x; b1 += xb * wv.y; b2 += xb * wv.z; b3 += xb * wv.w;
    }
    float4* o0 = (float4*)(xw + (size_t)(rowBase + 2 * slot) * FDIM + c4);
    float4* o1 = (float4*)(xw + (size_t)(rowBase + 2 * slot + 1) * FDIM + c4);
    *o0 = make_float4(a0, a1, a2, a3);
    *o1 = make_float4(b0, b1, b2, b3);
  }
}

// ---------------------------------------------------------------------------
// K8: per-node gather + tanh + w_lin dot + bias (fused epilogue).
// One wave (64 lanes) per dst node; lane holds features 2*lane, 2*lane+1.
// ---------------------------------------------------------------------------
__global__ __launch_bounds__(256) void gather_kernel(
    const float* __restrict__ xw, const int* __restrict__ offs,
    const int* __restrict__ csr_src, const float* __restrict__ csr_w,
    const float* __restrict__ dinv, const float* __restrict__ wl,
    const float* __restrict__ bl, float* __restrict__ out, int n) {
  int wid = (int)((blockIdx.x * (size_t)blockDim.x + threadIdx.x) >> 6);
  int lane = threadIdx.x & 63;
  if (wid >= n) return;
  const float2* xw2 = (const float2*)xw;
  float di = dinv[wid];
  float2 v = xw2[(size_t)wid * 64 + lane];
  float sn = di * di;  // self-loop norm = dinv*1*dinv
  float ax = sn * v.x, ay = sn * v.y;
  int beg = offs[wid], end = offs[wid + 1];
  for (int e = beg; e < end; e++) {
    int s = csr_src[e];
    float wn = csr_w[e];
    float2 u = xw2[(size_t)s * 64 + lane];
    ax += wn * u.x;
    ay += wn * u.y;
  }
  float2 wv = ((const float2*)wl)[lane];
  float p = tanhf(ax) * wv.x + tanhf(ay) * wv.y;
#pragma unroll
  for (int o = 32; o > 0; o >>= 1) p += __shfl_down(p, o, 64);
  if (lane == 0) out[wid] = p + bl[0];
}

// ---------------------------------------------------------------------------
extern "C" void kernel_launch(void* const* d_in, const int* in_sizes, int n_in,
                              void* d_out, int out_size, void* d_ws,
                              size_t ws_size, hipStream_t stream) {
  const float* x = (const float*)d_in[0];     // (N,128)
  const int* ei = (const int*)d_in[1];        // (2,E)
  const float* ew = (const float*)d_in[2];    // (E,)
  const float* W0 = (const float*)d_in[3];    // (128,128)
  const float* Wih = (const float*)d_in[4];   // (384,128)
  const float* Whh = (const float*)d_in[5];   // (384,128)
  const float* bih = (const float*)d_in[6];   // (384,)
  const float* bhh = (const float*)d_in[7];   // (384,)
  const float* wl = (const float*)d_in[8];    // (1,128)
  const float* bl = (const float*)d_in[9];    // (1,)
  float* out = (float*)d_out;                 // (N,1)

  // Workspace layout (fp32 units, all 16B-aligned)
  float* ws = (float*)d_ws;
  float* W_ev = ws;                           // 16384
  float* xw = W_ev + 16384;                   // 6,400,000
  float* deg = xw + (size_t)N_NODES * FDIM;   // 50000
  float* dinv = deg + N_NODES;                // 50000
  int* cnt = (int*)(dinv + N_NODES);          // 50000
  int* offs = cnt + N_NODES;                  // 50004 (padded)
  int* cur = offs + 50004;                    // 50004 (padded)
  int* csr_src = cur + 50004;                 // 800000
  float* csr_w = (float*)(csr_src + N_EDGES); // 800000
  int* part = (int*)(csr_w + N_EDGES);        // 256

  // K1: evolve W
  evolve_kernel<<<FDIM, 384, 0, stream>>>(W0, Wih, Whh, bih, bhh, W_ev);
  // K2: init
  init_deg_kernel<<<(N_NODES + 255) / 256, 256, 0, stream>>>(deg, cnt, N_NODES);
  // K3: histogram
  hist_kernel<<<(N_EDGES + 255) / 256, 256, 0, stream>>>(ei, ew, deg, cnt,
                                                         N_EDGES);
  // K5a: block partial sums + dinv
  partial_kernel<<<SCAN_BLOCKS, 256, 0, stream>>>(cnt, deg, dinv, part,
                                                  N_NODES);
  // K5b: scan partials
  scan_part_kernel<<<1, 256, 0, stream>>>(part);
  // K5c: final scan -> offs, cur
  scan_final_kernel<<<SCAN_BLOCKS, 256, 0, stream>>>(cnt, part, offs, cur,
                                                     N_NODES);
  // K6: scatter to CSR
  scatter_kernel<<<(N_EDGES + 255) / 256, 256, 0, stream>>>(
      ei, ew, dinv, cur, csr_src, csr_w, N_EDGES);
  // K7: xw = x @ W_ev
  xw_kernel<<<625, 256, 0, stream>>>(x, W_ev, xw, N_NODES);
  // K8: fused gather + tanh + linear
  gather_kernel<<<(N_NODES * 64) / 256, 256, 0, stream>>>(
      xw, offs, csr_src, csr_w, dinv, wl, bl, out, N_NODES);
}

// Round 3
// 292.802 us; speedup vs baseline: 1.6217x; 1.2249x over previous
//
#include <hip/hip_runtime.h>
#include <hip/hip_bf16.h>
#include <math.h>

#define N_NODES 50000
#define N_EDGES 800000
#define FDIM 128
#define SCAN_BLOCKS 196  // ceil(50000/256)

typedef unsigned int uint32;
typedef unsigned short ushort16;

// round-to-nearest-even fp32 -> bf16 (finite inputs)
__device__ inline unsigned short f2bf(float f) {
  unsigned int u = __float_as_uint(f);
  unsigned int r = u + 0x7fffu + ((u >> 16) & 1u);
  return (unsigned short)(r >> 16);
}

// ---------------------------------------------------------------------------
// K1: GRU-evolve the weight matrix (128x128). One block per row of W0.
// ---------------------------------------------------------------------------
__global__ __launch_bounds__(384) void evolve_kernel(
    const float* __restrict__ W0, const float* __restrict__ Wih,
    const float* __restrict__ Whh, const float* __restrict__ bih,
    const float* __restrict__ bhh, float* __restrict__ W) {
  int i = blockIdx.x;       // 0..127
  int jj = threadIdx.x;     // 0..383
  __shared__ float w0s[FDIM];
  __shared__ float gis[3 * FDIM];
  __shared__ float ghs[3 * FDIM];
  if (jj < FDIM) w0s[jj] = W0[i * FDIM + jj];
  __syncthreads();
  float gi = bih[jj], gh = bhh[jj];
  const float4* wih4 = (const float4*)(Wih + jj * FDIM);
  const float4* whh4 = (const float4*)(Whh + jj * FDIM);
#pragma unroll 8
  for (int k = 0; k < FDIM / 4; k++) {
    float4 a = wih4[k];
    float4 b = whh4[k];
    float w0a = w0s[4 * k], w0b = w0s[4 * k + 1];
    float w0c = w0s[4 * k + 2], w0d = w0s[4 * k + 3];
    gi += a.x * w0a + a.y * w0b + a.z * w0c + a.w * w0d;
    gh += b.x * w0a + b.y * w0b + b.z * w0c + b.w * w0d;
  }
  gis[jj] = gi;
  ghs[jj] = gh;
  __syncthreads();
  if (jj < FDIM) {
    float r = 1.0f / (1.0f + expf(-(gis[jj] + ghs[jj])));
    float z = 1.0f / (1.0f + expf(-(gis[jj + FDIM] + ghs[jj + FDIM])));
    float nn = tanhf(gis[jj + 2 * FDIM] + r * ghs[jj + 2 * FDIM]);
    W[i * FDIM + jj] = (1.0f - z) * nn + z * w0s[jj];
  }
}

// ---------------------------------------------------------------------------
// K2: init deg = 1.0 (self-loop weight), cnt = 0
// ---------------------------------------------------------------------------
__global__ void init_deg_kernel(float* __restrict__ deg, int* __restrict__ cnt,
                                int n) {
  int i = blockIdx.x * blockDim.x + threadIdx.x;
  if (i < n) {
    deg[i] = 1.0f;
    cnt[i] = 0;
  }
}

// ---------------------------------------------------------------------------
// K3: histogram — weighted degree + per-edge rank within its dst bucket
// (rank replaces the scatter-phase atomic)
// ---------------------------------------------------------------------------
__global__ void hist_kernel(const int* __restrict__ ei,
                            const float* __restrict__ ew,
                            float* __restrict__ deg, int* __restrict__ cnt,
                            int* __restrict__ rank, int e) {
  int idx = blockIdx.x * blockDim.x + threadIdx.x;
  if (idx < e) {
    int dst = ei[N_EDGES + idx];
    atomicAdd(&deg[dst], ew[idx]);
    rank[idx] = atomicAdd(&cnt[dst], 1);
  }
}

// ---------------------------------------------------------------------------
// K5a: per-block partial sums of cnt + fused dinv compute.
// ---------------------------------------------------------------------------
__global__ __launch_bounds__(256) void partial_kernel(
    const int* __restrict__ cnt, const float* __restrict__ deg,
    float* __restrict__ dinv, int* __restrict__ part, int n) {
  int t = threadIdx.x;
  int idx = blockIdx.x * 256 + t;
  int v = (idx < n) ? cnt[idx] : 0;
  if (idx < n) {
    float d = deg[idx];
    dinv[idx] = (d > 0.0f) ? rsqrtf(d) : 0.0f;
  }
  int r = v;
#pragma unroll
  for (int o = 32; o > 0; o >>= 1) r += __shfl_down(r, o, 64);
  __shared__ int s[4];
  if ((t & 63) == 0) s[t >> 6] = r;
  __syncthreads();
  if (t == 0) part[blockIdx.x] = s[0] + s[1] + s[2] + s[3];
}

// ---------------------------------------------------------------------------
// K5b: exclusive scan of SCAN_BLOCKS partials (single small block).
// ---------------------------------------------------------------------------
__global__ __launch_bounds__(256) void scan_part_kernel(int* __restrict__ part) {
  __shared__ int tmp[256];
  int t = threadIdx.x;
  int v = (t < SCAN_BLOCKS) ? part[t] : 0;
  tmp[t] = v;
  __syncthreads();
#pragma unroll
  for (int off = 1; off < 256; off <<= 1) {
    int u = (t >= off) ? tmp[t - off] : 0;
    __syncthreads();
    tmp[t] += u;
    __syncthreads();
  }
  if (t < SCAN_BLOCKS) part[t] = tmp[t] - v;  // exclusive
}

// ---------------------------------------------------------------------------
// K5c: per-block local exclusive scan + partial offset -> offs
// ---------------------------------------------------------------------------
__global__ __launch_bounds__(256) void scan_final_kernel(
    const int* __restrict__ cnt, const int* __restrict__ part,
    int* __restrict__ offs, int n) {
  __shared__ int tmp[256];
  int t = threadIdx.x;
  int idx = blockIdx.x * 256 + t;
  int v = (idx < n) ? cnt[idx] : 0;
  tmp[t] = v;
  __syncthreads();
#pragma unroll
  for (int off = 1; off < 256; off <<= 1) {
    int u = (t >= off) ? tmp[t - off] : 0;
    __syncthreads();
    tmp[t] += u;
    __syncthreads();
  }
  int excl = part[blockIdx.x] + tmp[t] - v;
  if (idx < n) offs[idx] = excl;
  if (idx == n - 1) offs[n] = excl + v;
}

// ---------------------------------------------------------------------------
// K6: scatter edges into CSR-by-dst (no atomics: pos = offs[dst]+rank).
// CSR entry packed as int2{src, norm-bits}.
// ---------------------------------------------------------------------------
__global__ void scatter_kernel(const int* __restrict__ ei,
                               const float* __restrict__ ew,
                               const float* __restrict__ dinv,
                               const int* __restrict__ offs,
                               const int* __restrict__ rank,
                               int2* __restrict__ csr, int e) {
  int idx = blockIdx.x * blockDim.x + threadIdx.x;
  if (idx < e) {
    int src = ei[idx];
    int dst = ei[N_EDGES + idx];
    float nrm = dinv[src] * ew[idx] * dinv[dst];
    int pos = offs[dst] + rank[idx];
    csr[pos] = make_int2(src, __float_as_int(nrm));
  }
}

// ---------------------------------------------------------------------------
// K7: xw = x @ W (fp32 math, LDS-staged W), output packed bf16.
// ---------------------------------------------------------------------------
__global__ __launch_bounds__(256) void xw_kernel(const float* __restrict__ x,
                                                 const float* __restrict__ W,
                                                 unsigned short* __restrict__ xw,
                                                 int n) {
  __shared__ float Ws[FDIM * FDIM];  // 64 KiB
  __shared__ float xs[16 * FDIM];    // 8 KiB
  int t = threadIdx.x;
  const float4* W4 = (const float4*)W;
  float4* Ws4 = (float4*)Ws;
#pragma unroll
  for (int i = 0; i < 16; i++) Ws4[i * 256 + t] = W4[i * 256 + t];
  int c4 = (t & 31) * 4;
  int slot = t >> 5;  // 0..7
  for (int rowBase = blockIdx.x * 16; rowBase < n; rowBase += gridDim.x * 16) {
    __syncthreads();
    float4* xs4 = (float4*)xs;
    const float4* xg = (const float4*)(x + (size_t)rowBase * FDIM);
    xs4[t] = xg[t];
    xs4[256 + t] = xg[256 + t];
    __syncthreads();
    float a0 = 0, a1 = 0, a2 = 0, a3 = 0;
    float b0 = 0, b1 = 0, b2 = 0, b3 = 0;
    const float* x0 = xs + (2 * slot) * FDIM;
    const float* x1 = x0 + FDIM;
#pragma unroll 4
    for (int k = 0; k < FDIM; k++) {
      float4 wv = *((const float4*)(Ws + k * FDIM + c4));
      float xa = x0[k], xb = x1[k];
      a0 += xa * wv.x; a1 += xa * wv.y; a2 += xa * wv.z; a3 += xa * wv.w;
      b0 += xb * wv.x; b1 += xb * wv.y; b2 += xb * wv.z; b3 += xb * wv.w;
    }
    ushort4 pa = make_ushort4(f2bf(a0), f2bf(a1), f2bf(a2), f2bf(a3));
    ushort4 pb = make_ushort4(f2bf(b0), f2bf(b1), f2bf(b2), f2bf(b3));
    *(ushort4*)(xw + (size_t)(rowBase + 2 * slot) * FDIM + c4) = pa;
    *(ushort4*)(xw + (size_t)(rowBase + 2 * slot + 1) * FDIM + c4) = pb;
  }
}

// ---------------------------------------------------------------------------
// K8: per-node gather (bf16 rows) + tanh + w_lin dot + bias.
// One wave per dst node; lane loads 1 dword = 2 bf16 features.
// Edge loop unrolled x4 for memory-level parallelism.
// ---------------------------------------------------------------------------
__global__ __launch_bounds__(256) void gather_kernel(
    const uint32* __restrict__ xwb, const int* __restrict__ offs,
    const int2* __restrict__ csr, const float* __restrict__ dinv,
    const float* __restrict__ wl, const float* __restrict__ bl,
    float* __restrict__ out, int n) {
  int wid = (int)((blockIdx.x * (size_t)blockDim.x + threadIdx.x) >> 6);
  int lane = threadIdx.x & 63;
  if (wid >= n) return;
  float di = dinv[wid];
  float sn = di * di;  // self-loop norm
  uint32 uv = xwb[(size_t)wid * 64 + lane];
  float ax = sn * __uint_as_float(uv << 16);
  float ay = sn * __uint_as_float(uv & 0xffff0000u);
  int beg = offs[wid], end = offs[wid + 1];
  int e = beg;
  for (; e + 4 <= end; e += 4) {
    int2 c0 = csr[e];
    int2 c1 = csr[e + 1];
    int2 c2 = csr[e + 2];
    int2 c3 = csr[e + 3];
    uint32 u0 = xwb[(size_t)c0.x * 64 + lane];
    uint32 u1 = xwb[(size_t)c1.x * 64 + lane];
    uint32 u2 = xwb[(size_t)c2.x * 64 + lane];
    uint32 u3 = xwb[(size_t)c3.x * 64 + lane];
    float w0 = __int_as_float(c0.y), w1 = __int_as_float(c1.y);
    float w2 = __int_as_float(c2.y), w3 = __int_as_float(c3.y);
    ax += w0 * __uint_as_float(u0 << 16);
    ay += w0 * __uint_as_float(u0 & 0xffff0000u);
    ax += w1 * __uint_as_float(u1 << 16);
    ay += w1 * __uint_as_float(u1 & 0xffff0000u);
    ax += w2 * __uint_as_float(u2 << 16);
    ay += w2 * __uint_as_float(u2 & 0xffff0000u);
    ax += w3 * __uint_as_float(u3 << 16);
    ay += w3 * __uint_as_float(u3 & 0xffff0000u);
  }
  for (; e < end; e++) {
    int2 c = csr[e];
    uint32 u = xwb[(size_t)c.x * 64 + lane];
    float wn = __int_as_float(c.y);
    ax += wn * __uint_as_float(u << 16);
    ay += wn * __uint_as_float(u & 0xffff0000u);
  }
  float2 wv = ((const float2*)wl)[lane];
  float p = tanhf(ax) * wv.x + tanhf(ay) * wv.y;
#pragma unroll
  for (int o = 32; o > 0; o >>= 1) p += __shfl_down(p, o, 64);
  if (lane == 0) out[wid] = p + bl[0];
}

// ---------------------------------------------------------------------------
extern "C" void kernel_launch(void* const* d_in, const int* in_sizes, int n_in,
                              void* d_out, int out_size, void* d_ws,
                              size_t ws_size, hipStream_t stream) {
  const float* x = (const float*)d_in[0];     // (N,128)
  const int* ei = (const int*)d_in[1];        // (2,E)
  const float* ew = (const float*)d_in[2];    // (E,)
  const float* W0 = (const float*)d_in[3];    // (128,128)
  const float* Wih = (const float*)d_in[4];   // (384,128)
  const float* Whh = (const float*)d_in[5];   // (384,128)
  const float* bih = (const float*)d_in[6];   // (384,)
  const float* bhh = (const float*)d_in[7];   // (384,)
  const float* wl = (const float*)d_in[8];    // (1,128)
  const float* bl = (const float*)d_in[9];    // (1,)
  float* out = (float*)d_out;                 // (N,1)

  // Workspace layout (fp32 units, all 16B-aligned)
  float* ws = (float*)d_ws;
  float* W_ev = ws;                                 // 16384
  unsigned short* xw = (unsigned short*)(W_ev + 16384);  // 6.4M bf16 = 3.2M f32
  float* deg = (float*)(xw + (size_t)N_NODES * FDIM);    // 50000
  float* dinv = deg + N_NODES;                      // 50000
  int* cnt = (int*)(dinv + N_NODES);                // 50000
  int* rank = cnt + N_NODES;                        // 800000
  int* offs = rank + N_EDGES;                       // 50004 (padded)
  int2* csr = (int2*)(offs + 50004);                // 800000 int2
  int* part = (int*)(csr + N_EDGES);                // 256

  // K1: evolve W
  evolve_kernel<<<FDIM, 384, 0, stream>>>(W0, Wih, Whh, bih, bhh, W_ev);
  // K2: init
  init_deg_kernel<<<(N_NODES + 255) / 256, 256, 0, stream>>>(deg, cnt, N_NODES);
  // K3: histogram + rank
  hist_kernel<<<(N_EDGES + 255) / 256, 256, 0, stream>>>(ei, ew, deg, cnt,
                                                         rank, N_EDGES);
  // K5a: block partial sums + dinv
  partial_kernel<<<SCAN_BLOCKS, 256, 0, stream>>>(cnt, deg, dinv, part,
                                                  N_NODES);
  // K5b: scan partials
  scan_part_kernel<<<1, 256, 0, stream>>>(part);
  // K5c: final scan -> offs
  scan_final_kernel<<<SCAN_BLOCKS, 256, 0, stream>>>(cnt, part, offs, N_NODES);
  // K6: scatter to CSR (no atomics)
  scatter_kernel<<<(N_EDGES + 255) / 256, 256, 0, stream>>>(
      ei, ew, dinv, offs, rank, csr, N_EDGES);
  // K7: xw = x @ W_ev -> bf16
  xw_kernel<<<625, 256, 0, stream>>>(x, W_ev, xw, N_NODES);
  // K8: fused gather + tanh + linear
  gather_kernel<<<(N_NODES * 64) / 256, 256, 0, stream>>>(
      (const uint32*)xw, offs, csr, dinv, wl, bl, out, N_NODES);
}

// Round 4
// 249.421 us; speedup vs baseline: 1.9037x; 1.1739x over previous
//
#include <hip/hip_runtime.h>
#include <hip/hip_bf16.h>
#include <math.h>

#define N_NODES 50000
#define N_EDGES 800000
#define FDIM 128
#define SCAN_BLOCKS 196  // ceil(50000/256)

typedef unsigned int uint32;

// round-to-nearest-even fp32 -> bf16 (finite inputs)
__device__ inline unsigned short f2bf(float f) {
  unsigned int u = __float_as_uint(f);
  unsigned int r = u + 0x7fffu + ((u >> 16) & 1u);
  return (unsigned short)(r >> 16);
}

// ---------------------------------------------------------------------------
// K1: GRU-evolve the weight matrix (128x128). One block per row of W0.
// ---------------------------------------------------------------------------
__global__ __launch_bounds__(384) void evolve_kernel(
    const float* __restrict__ W0, const float* __restrict__ Wih,
    const float* __restrict__ Whh, const float* __restrict__ bih,
    const float* __restrict__ bhh, float* __restrict__ W) {
  int i = blockIdx.x;       // 0..127
  int jj = threadIdx.x;     // 0..383
  __shared__ float w0s[FDIM];
  __shared__ float gis[3 * FDIM];
  __shared__ float ghs[3 * FDIM];
  if (jj < FDIM) w0s[jj] = W0[i * FDIM + jj];
  __syncthreads();
  float gi = bih[jj], gh = bhh[jj];
  const float4* wih4 = (const float4*)(Wih + jj * FDIM);
  const float4* whh4 = (const float4*)(Whh + jj * FDIM);
#pragma unroll 8
  for (int k = 0; k < FDIM / 4; k++) {
    float4 a = wih4[k];
    float4 b = whh4[k];
    float w0a = w0s[4 * k], w0b = w0s[4 * k + 1];
    float w0c = w0s[4 * k + 2], w0d = w0s[4 * k + 3];
    gi += a.x * w0a + a.y * w0b + a.z * w0c + a.w * w0d;
    gh += b.x * w0a + b.y * w0b + b.z * w0c + b.w * w0d;
  }
  gis[jj] = gi;
  ghs[jj] = gh;
  __syncthreads();
  if (jj < FDIM) {
    float r = 1.0f / (1.0f + expf(-(gis[jj] + ghs[jj])));
    float z = 1.0f / (1.0f + expf(-(gis[jj + FDIM] + ghs[jj + FDIM])));
    float nn = tanhf(gis[jj + 2 * FDIM] + r * ghs[jj + 2 * FDIM]);
    W[i * FDIM + jj] = (1.0f - z) * nn + z * w0s[jj];
  }
}

// ---------------------------------------------------------------------------
// K2: init cnt = 0
// ---------------------------------------------------------------------------
__global__ void init_cnt_kernel(int* __restrict__ cnt, int n) {
  int i = blockIdx.x * blockDim.x + threadIdx.x;
  if (i < n) cnt[i] = 0;
}

// ---------------------------------------------------------------------------
// K3: per-edge rank within its dst bucket (the ONLY atomic pass: 1/edge)
// ---------------------------------------------------------------------------
__global__ void hist_kernel(const int* __restrict__ ei, int* __restrict__ cnt,
                            int* __restrict__ rank, int e) {
  int idx = blockIdx.x * blockDim.x + threadIdx.x;
  if (idx < e) {
    int dst = ei[N_EDGES + idx];
    rank[idx] = atomicAdd(&cnt[dst], 1);
  }
}

// ---------------------------------------------------------------------------
// K5a: per-block partial sums of cnt.
// ---------------------------------------------------------------------------
__global__ __launch_bounds__(256) void partial_kernel(
    const int* __restrict__ cnt, int* __restrict__ part, int n) {
  int t = threadIdx.x;
  int idx = blockIdx.x * 256 + t;
  int v = (idx < n) ? cnt[idx] : 0;
  int r = v;
#pragma unroll
  for (int o = 32; o > 0; o >>= 1) r += __shfl_down(r, o, 64);
  __shared__ int s[4];
  if ((t & 63) == 0) s[t >> 6] = r;
  __syncthreads();
  if (t == 0) part[blockIdx.x] = s[0] + s[1] + s[2] + s[3];
}

// ---------------------------------------------------------------------------
// K5b: exclusive scan of SCAN_BLOCKS partials (single small block).
// ---------------------------------------------------------------------------
__global__ __launch_bounds__(256) void scan_part_kernel(int* __restrict__ part) {
  __shared__ int tmp[256];
  int t = threadIdx.x;
  int v = (t < SCAN_BLOCKS) ? part[t] : 0;
  tmp[t] = v;
  __syncthreads();
#pragma unroll
  for (int off = 1; off < 256; off <<= 1) {
    int u = (t >= off) ? tmp[t - off] : 0;
    __syncthreads();
    tmp[t] += u;
    __syncthreads();
  }
  if (t < SCAN_BLOCKS) part[t] = tmp[t] - v;  // exclusive
}

// ---------------------------------------------------------------------------
// K5c: per-block local exclusive scan + partial offset -> offs
// ---------------------------------------------------------------------------
__global__ __launch_bounds__(256) void scan_final_kernel(
    const int* __restrict__ cnt, const int* __restrict__ part,
    int* __restrict__ offs, int n) {
  __shared__ int tmp[256];
  int t = threadIdx.x;
  int idx = blockIdx.x * 256 + t;
  int v = (idx < n) ? cnt[idx] : 0;
  tmp[t] = v;
  __syncthreads();
#pragma unroll
  for (int off = 1; off < 256; off <<= 1) {
    int u = (t >= off) ? tmp[t - off] : 0;
    __syncthreads();
    tmp[t] += u;
    __syncthreads();
  }
  int excl = part[blockIdx.x] + tmp[t] - v;
  if (idx < n) offs[idx] = excl;
  if (idx == n - 1) offs[n] = excl + v;
}

// ---------------------------------------------------------------------------
// K6: scatter edges into CSR-by-dst (no atomics: pos = offs[dst]+rank).
// CSR entry packed as int2{src, raw-edge-weight bits}.
// ---------------------------------------------------------------------------
__global__ void scatter_kernel(const int* __restrict__ ei,
                               const float* __restrict__ ew,
                               const int* __restrict__ offs,
                               const int* __restrict__ rank,
                               int2* __restrict__ csr, int e) {
  int idx = blockIdx.x * blockDim.x + threadIdx.x;
  if (idx < e) {
    int src = ei[idx];
    int dst = ei[N_EDGES + idx];
    int pos = offs[dst] + rank[idx];
    csr[pos] = make_int2(src, __float_as_int(ew[idx]));
  }
}

// ---------------------------------------------------------------------------
// K6b: deg from finished CSR (atomic-free) -> dinv. One thread per node.
// deg = 1 (self-loop) + sum of edge weights in this node's bucket.
// ---------------------------------------------------------------------------
__global__ __launch_bounds__(256) void deg_dinv_kernel(
    const int2* __restrict__ csr, const int* __restrict__ offs,
    float* __restrict__ dinv, int n) {
  int i = blockIdx.x * blockDim.x + threadIdx.x;
  if (i >= n) return;
  int b = offs[i], e = offs[i + 1];
  float d = 1.0f;
  for (int j = b; j < e; j++) d += __int_as_float(csr[j].y);
  dinv[i] = (d > 0.0f) ? rsqrtf(d) : 0.0f;
}

// ---------------------------------------------------------------------------
// K7: y = dinv[row] * (x @ W), output packed bf16.
// ---------------------------------------------------------------------------
__global__ __launch_bounds__(256) void xw_kernel(const float* __restrict__ x,
                                                 const float* __restrict__ W,
                                                 const float* __restrict__ dinv,
                                                 unsigned short* __restrict__ y,
                                                 int n) {
  __shared__ float Ws[FDIM * FDIM];  // 64 KiB
  __shared__ float xs[16 * FDIM];    // 8 KiB
  int t = threadIdx.x;
  const float4* W4 = (const float4*)W;
  float4* Ws4 = (float4*)Ws;
#pragma unroll
  for (int i = 0; i < 16; i++) Ws4[i * 256 + t] = W4[i * 256 + t];
  int c4 = (t & 31) * 4;
  int slot = t >> 5;  // 0..7
  for (int rowBase = blockIdx.x * 16; rowBase < n; rowBase += gridDim.x * 16) {
    __syncthreads();
    float4* xs4 = (float4*)xs;
    const float4* xg = (const float4*)(x + (size_t)rowBase * FDIM);
    xs4[t] = xg[t];
    xs4[256 + t] = xg[256 + t];
    __syncthreads();
    float a0 = 0, a1 = 0, a2 = 0, a3 = 0;
    float b0 = 0, b1 = 0, b2 = 0, b3 = 0;
    const float* x0 = xs + (2 * slot) * FDIM;
    const float* x1 = x0 + FDIM;
#pragma unroll 4
    for (int k = 0; k < FDIM; k++) {
      float4 wv = *((const float4*)(Ws + k * FDIM + c4));
      float xa = x0[k], xb = x1[k];
      a0 += xa * wv.x; a1 += xa * wv.y; a2 += xa * wv.z; a3 += xa * wv.w;
      b0 += xb * wv.x; b1 += xb * wv.y; b2 += xb * wv.z; b3 += xb * wv.w;
    }
    float da = dinv[rowBase + 2 * slot];
    float db = dinv[rowBase + 2 * slot + 1];
    ushort4 pa = make_ushort4(f2bf(da * a0), f2bf(da * a1), f2bf(da * a2),
                              f2bf(da * a3));
    ushort4 pb = make_ushort4(f2bf(db * b0), f2bf(db * b1), f2bf(db * b2),
                              f2bf(db * b3));
    *(ushort4*)(y + (size_t)(rowBase + 2 * slot) * FDIM + c4) = pa;
    *(ushort4*)(y + (size_t)(rowBase + 2 * slot + 1) * FDIM + c4) = pb;
  }
}

// ---------------------------------------------------------------------------
// K8: per-node gather (bf16 y rows) + tanh + w_lin dot + bias.
// h[dst] = tanh( dinv[dst] * ( y[dst] + sum_e w_e * y[src_e] ) )
// One wave per dst node; lane loads 1 dword = 2 bf16 features.
// ---------------------------------------------------------------------------
__global__ __launch_bounds__(256) void gather_kernel(
    const uint32* __restrict__ yb, const int* __restrict__ offs,
    const int2* __restrict__ csr, const float* __restrict__ dinv,
    const float* __restrict__ wl, const float* __restrict__ bl,
    float* __restrict__ out, int n) {
  int wid = (int)((blockIdx.x * (size_t)blockDim.x + threadIdx.x) >> 6);
  int lane = threadIdx.x & 63;
  if (wid >= n) return;
  float di = dinv[wid];
  uint32 uv = yb[(size_t)wid * 64 + lane];
  float ax = __uint_as_float(uv << 16);          // self term, coeff 1
  float ay = __uint_as_float(uv & 0xffff0000u);
  int beg = offs[wid], end = offs[wid + 1];
  int e = beg;
  for (; e + 4 <= end; e += 4) {
    int2 c0 = csr[e];
    int2 c1 = csr[e + 1];
    int2 c2 = csr[e + 2];
    int2 c3 = csr[e + 3];
    uint32 u0 = yb[(size_t)c0.x * 64 + lane];
    uint32 u1 = yb[(size_t)c1.x * 64 + lane];
    uint32 u2 = yb[(size_t)c2.x * 64 + lane];
    uint32 u3 = yb[(size_t)c3.x * 64 + lane];
    float w0 = __int_as_float(c0.y), w1 = __int_as_float(c1.y);
    float w2 = __int_as_float(c2.y), w3 = __int_as_float(c3.y);
    ax += w0 * __uint_as_float(u0 << 16);
    ay += w0 * __uint_as_float(u0 & 0xffff0000u);
    ax += w1 * __uint_as_float(u1 << 16);
    ay += w1 * __uint_as_float(u1 & 0xffff0000u);
    ax += w2 * __uint_as_float(u2 << 16);
    ay += w2 * __uint_as_float(u2 & 0xffff0000u);
    ax += w3 * __uint_as_float(u3 << 16);
    ay += w3 * __uint_as_float(u3 & 0xffff0000u);
  }
  for (; e < end; e++) {
    int2 c = csr[e];
    uint32 u = yb[(size_t)c.x * 64 + lane];
    float wn = __int_as_float(c.y);
    ax += wn * __uint_as_float(u << 16);
    ay += wn * __uint_as_float(u & 0xffff0000u);
  }
  float2 wv = ((const float2*)wl)[lane];
  float p = tanhf(di * ax) * wv.x + tanhf(di * ay) * wv.y;
#pragma unroll
  for (int o = 32; o > 0; o >>= 1) p += __shfl_down(p, o, 64);
  if (lane == 0) out[wid] = p + bl[0];
}

// ---------------------------------------------------------------------------
extern "C" void kernel_launch(void* const* d_in, const int* in_sizes, int n_in,
                              void* d_out, int out_size, void* d_ws,
                              size_t ws_size, hipStream_t stream) {
  const float* x = (const float*)d_in[0];     // (N,128)
  const int* ei = (const int*)d_in[1];        // (2,E)
  const float* ew = (const float*)d_in[2];    // (E,)
  const float* W0 = (const float*)d_in[3];    // (128,128)
  const float* Wih = (const float*)d_in[4];   // (384,128)
  const float* Whh = (const float*)d_in[5];   // (384,128)
  const float* bih = (const float*)d_in[6];   // (384,)
  const float* bhh = (const float*)d_in[7];   // (384,)
  const float* wl = (const float*)d_in[8];    // (1,128)
  const float* bl = (const float*)d_in[9];    // (1,)
  float* out = (float*)d_out;                 // (N,1)

  // Workspace layout (all 16B-aligned)
  float* ws = (float*)d_ws;
  float* W_ev = ws;                                      // 16384 f
  unsigned short* y = (unsigned short*)(W_ev + 16384);   // N*128 bf16
  float* dinv = (float*)(y + (size_t)N_NODES * FDIM);    // 50000 f
  int* cnt = (int*)(dinv + N_NODES);                     // 50000 i
  int* rank = cnt + N_NODES;                             // 800000 i
  int* offs = rank + N_EDGES;                            // 50004 i (padded)
  int2* csr = (int2*)(offs + 50004);                     // 800000 int2
  int* part = (int*)(csr + N_EDGES);                     // 256 i

  // K1: evolve W
  evolve_kernel<<<FDIM, 384, 0, stream>>>(W0, Wih, Whh, bih, bhh, W_ev);
  // K2: init cnt
  init_cnt_kernel<<<(N_NODES + 255) / 256, 256, 0, stream>>>(cnt, N_NODES);
  // K3: rank histogram (single atomic per edge)
  hist_kernel<<<(N_EDGES + 255) / 256, 256, 0, stream>>>(ei, cnt, rank,
                                                         N_EDGES);
  // K5a: block partial sums
  partial_kernel<<<SCAN_BLOCKS, 256, 0, stream>>>(cnt, part, N_NODES);
  // K5b: scan partials
  scan_part_kernel<<<1, 256, 0, stream>>>(part);
  // K5c: final scan -> offs
  scan_final_kernel<<<SCAN_BLOCKS, 256, 0, stream>>>(cnt, part, offs, N_NODES);
  // K6: scatter to CSR (no atomics)
  scatter_kernel<<<(N_EDGES + 255) / 256, 256, 0, stream>>>(ei, ew, offs, rank,
                                                            csr, N_EDGES);
  // K6b: deg from CSR -> dinv (atomic-free)
  deg_dinv_kernel<<<(N_NODES + 255) / 256, 256, 0, stream>>>(csr, offs, dinv,
                                                             N_NODES);
  // K7: y = dinv * (x @ W_ev) -> bf16
  xw_kernel<<<625, 256, 0, stream>>>(x, W_ev, dinv, y, N_NODES);
  // K8: fused gather + tanh + linear
  gather_kernel<<<(N_NODES * 64) / 256, 256, 0, stream>>>(
      (const uint32*)y, offs, csr, dinv, wl, bl, out, N_NODES);
}

// Round 5
// 214.210 us; speedup vs baseline: 2.2167x; 1.1644x over previous
//
#include <hip/hip_runtime.h>
#include <hip/hip_bf16.h>
#include <math.h>

#define N_NODES 50000
#define N_EDGES 800000
#define FDIM 128
#define SCAN_BLOCKS 196  // ceil(50000/256)

typedef unsigned int uint32;
typedef __attribute__((ext_vector_type(8))) __bf16 bf16x8;
typedef __attribute__((ext_vector_type(8))) short short8;
typedef __attribute__((ext_vector_type(16))) float f32x16;

// round-to-nearest-even fp32 -> bf16 bits (finite inputs)
__device__ inline unsigned short f2bf(float f) {
  unsigned int u = __float_as_uint(f);
  unsigned int r = u + 0x7fffu + ((u >> 16) & 1u);
  return (unsigned short)(r >> 16);
}

// ---------------------------------------------------------------------------
// K1: GRU-evolve the weight matrix (128x128). One block per row of W0.
// ---------------------------------------------------------------------------
__global__ __launch_bounds__(384) void evolve_kernel(
    const float* __restrict__ W0, const float* __restrict__ Wih,
    const float* __restrict__ Whh, const float* __restrict__ bih,
    const float* __restrict__ bhh, float* __restrict__ W) {
  int i = blockIdx.x;       // 0..127
  int jj = threadIdx.x;     // 0..383
  __shared__ float w0s[FDIM];
  __shared__ float gis[3 * FDIM];
  __shared__ float ghs[3 * FDIM];
  if (jj < FDIM) w0s[jj] = W0[i * FDIM + jj];
  __syncthreads();
  float gi = bih[jj], gh = bhh[jj];
  const float4* wih4 = (const float4*)(Wih + jj * FDIM);
  const float4* whh4 = (const float4*)(Whh + jj * FDIM);
#pragma unroll 8
  for (int k = 0; k < FDIM / 4; k++) {
    float4 a = wih4[k];
    float4 b = whh4[k];
    float w0a = w0s[4 * k], w0b = w0s[4 * k + 1];
    float w0c = w0s[4 * k + 2], w0d = w0s[4 * k + 3];
    gi += a.x * w0a + a.y * w0b + a.z * w0c + a.w * w0d;
    gh += b.x * w0a + b.y * w0b + b.z * w0c + b.w * w0d;
  }
  gis[jj] = gi;
  ghs[jj] = gh;
  __syncthreads();
  if (jj < FDIM) {
    float r = 1.0f / (1.0f + expf(-(gis[jj] + ghs[jj])));
    float z = 1.0f / (1.0f + expf(-(gis[jj + FDIM] + ghs[jj + FDIM])));
    float nn = tanhf(gis[jj + 2 * FDIM] + r * ghs[jj + 2 * FDIM]);
    W[i * FDIM + jj] = (1.0f - z) * nn + z * w0s[jj];
  }
}

// ---------------------------------------------------------------------------
// K3: per-edge rank within its dst bucket (the ONLY atomic pass: 1/edge)
// ---------------------------------------------------------------------------
__global__ void hist_kernel(const int* __restrict__ ei, int* __restrict__ cnt,
                            int* __restrict__ rank, int e) {
  int idx = blockIdx.x * blockDim.x + threadIdx.x;
  if (idx < e) {
    int dst = ei[N_EDGES + idx];
    rank[idx] = atomicAdd(&cnt[dst], 1);
  }
}

// ---------------------------------------------------------------------------
// K5a: per-block partial sums of cnt.
// ---------------------------------------------------------------------------
__global__ __launch_bounds__(256) void partial_kernel(
    const int* __restrict__ cnt, int* __restrict__ part, int n) {
  int t = threadIdx.x;
  int idx = blockIdx.x * 256 + t;
  int v = (idx < n) ? cnt[idx] : 0;
  int r = v;
#pragma unroll
  for (int o = 32; o > 0; o >>= 1) r += __shfl_down(r, o, 64);
  __shared__ int s[4];
  if ((t & 63) == 0) s[t >> 6] = r;
  __syncthreads();
  if (t == 0) part[blockIdx.x] = s[0] + s[1] + s[2] + s[3];
}

// ---------------------------------------------------------------------------
// K5b: exclusive scan of SCAN_BLOCKS partials (single small block).
// ---------------------------------------------------------------------------
__global__ __launch_bounds__(256) void scan_part_kernel(int* __restrict__ part) {
  __shared__ int tmp[256];
  int t = threadIdx.x;
  int v = (t < SCAN_BLOCKS) ? part[t] : 0;
  tmp[t] = v;
  __syncthreads();
#pragma unroll
  for (int off = 1; off < 256; off <<= 1) {
    int u = (t >= off) ? tmp[t - off] : 0;
    __syncthreads();
    tmp[t] += u;
    __syncthreads();
  }
  if (t < SCAN_BLOCKS) part[t] = tmp[t] - v;  // exclusive
}

// ---------------------------------------------------------------------------
// K5c: per-block local exclusive scan + partial offset -> offs
// ---------------------------------------------------------------------------
__global__ __launch_bounds__(256) void scan_final_kernel(
    const int* __restrict__ cnt, const int* __restrict__ part,
    int* __restrict__ offs, int n) {
  __shared__ int tmp[256];
  int t = threadIdx.x;
  int idx = blockIdx.x * 256 + t;
  int v = (idx < n) ? cnt[idx] : 0;
  tmp[t] = v;
  __syncthreads();
#pragma unroll
  for (int off = 1; off < 256; off <<= 1) {
    int u = (t >= off) ? tmp[t - off] : 0;
    __syncthreads();
    tmp[t] += u;
    __syncthreads();
  }
  int excl = part[blockIdx.x] + tmp[t] - v;
  if (idx < n) offs[idx] = excl;
  if (idx == n - 1) offs[n] = excl + v;
}

// ---------------------------------------------------------------------------
// K6: scatter edges into CSR-by-dst (no atomics: pos = offs[dst]+rank).
// CSR entry packed as int2{src, raw-edge-weight bits}.
// ---------------------------------------------------------------------------
__global__ void scatter_kernel(const int* __restrict__ ei,
                               const float* __restrict__ ew,
                               const int* __restrict__ offs,
                               const int* __restrict__ rank,
                               int2* __restrict__ csr, int e) {
  int idx = blockIdx.x * blockDim.x + threadIdx.x;
  if (idx < e) {
    int src = ei[idx];
    int dst = ei[N_EDGES + idx];
    int pos = offs[dst] + rank[idx];
    csr[pos] = make_int2(src, __float_as_int(ew[idx]));
  }
}

// ---------------------------------------------------------------------------
// K6b: deg from finished CSR (atomic-free) -> dinv. One thread per node.
// ---------------------------------------------------------------------------
__global__ __launch_bounds__(256) void deg_dinv_kernel(
    const int2* __restrict__ csr, const int* __restrict__ offs,
    float* __restrict__ dinv, int n) {
  int i = blockIdx.x * blockDim.x + threadIdx.x;
  if (i >= n) return;
  int b = offs[i], e = offs[i + 1];
  float d = 1.0f;
  for (int j = b; j < e; j++) d += __int_as_float(csr[j].y);
  dinv[i] = (d > 0.0f) ? rsqrtf(d) : 0.0f;
}

// ---------------------------------------------------------------------------
// K7: y = dinv[row] * (x @ W) via bf16 MFMA (32x32x16), output packed bf16.
// One wave per 32-row tile. W staged once/block in LDS as bf16, frag-blocked:
// Bs[kg][n][j] = W[kg*8+j][n]  (kg=k/8: 16 groups, n: 128 cols, j: 0..7)
// so a B-fragment (8 consecutive k for fixed n) is one 16-B LDS read.
// A-frags come straight from global x (2 float4/lane/chunk, prefetched).
// ---------------------------------------------------------------------------
__global__ __launch_bounds__(256) void xw_mfma_kernel(
    const float* __restrict__ x, const float* __restrict__ W,
    const float* __restrict__ dinv, unsigned short* __restrict__ y, int n) {
  __shared__ short Bs[16 * 128 * 8];  // 32 KiB
  int t = threadIdx.x;
  // ---- stage W -> LDS (bf16, frag-blocked) ----
#pragma unroll
  for (int i = 0; i < 64; i++) {
    int idx = i * 256 + t;        // coalesced read of W[k][n]
    int k = idx >> 7, nn = idx & 127;
    Bs[(((k >> 3) << 7) + nn) * 8 + (k & 7)] = (short)f2bf(W[idx]);
  }
  __syncthreads();

  int lane = t & 63;
  int wid = blockIdx.x * 4 + (t >> 6);
  int tr = wid * 32;  // tile row base
  if (tr >= n) return;
  int m = lane & 31;   // A row / D col within tile
  int q2 = lane >> 5;  // half-wave: k-offset selector

  int row = tr + m;
  if (row >= n) row = n - 1;  // tail clamp (stores are guarded)
  const float* xr = x + (size_t)row * FDIM;

  // ---- load + convert 8 A-frags (16 float4 loads, unrolled => in flight) ----
  bf16x8 a[8];
#pragma unroll
  for (int kc = 0; kc < 8; kc++) {
    int k0 = kc * 16 + q2 * 8;
    float4 p = *(const float4*)(xr + k0);
    float4 q = *(const float4*)(xr + k0 + 4);
    short8 s;
    s[0] = (short)f2bf(p.x); s[1] = (short)f2bf(p.y);
    s[2] = (short)f2bf(p.z); s[3] = (short)f2bf(p.w);
    s[4] = (short)f2bf(q.x); s[5] = (short)f2bf(q.y);
    s[6] = (short)f2bf(q.z); s[7] = (short)f2bf(q.w);
    a[kc] = __builtin_bit_cast(bf16x8, s);
  }

  // ---- 4 col-tiles x 8 k-chunks MFMA ----
  f32x16 acc[4];
#pragma unroll
  for (int ct = 0; ct < 4; ct++) {
#pragma unroll
    for (int r = 0; r < 16; r++) acc[ct][r] = 0.0f;
  }
#pragma unroll
  for (int ct = 0; ct < 4; ct++) {
    int nn = ct * 32 + m;
#pragma unroll
    for (int kc = 0; kc < 8; kc++) {
      int kg = kc * 2 + q2;
      bf16x8 b = __builtin_bit_cast(
          bf16x8, *(const short8*)(Bs + (((kg << 7) + nn) << 3)));
      acc[ct] = __builtin_amdgcn_mfma_f32_32x32x16_bf16(a[kc], b, acc[ct], 0,
                                                        0, 0);
    }
  }

  // ---- epilogue: scale by dinv[row], pack bf16, store ----
  // D layout: col = lane&31, row = (reg&3) + 8*(reg>>2) + 4*(lane>>5)
#pragma unroll
  for (int r = 0; r < 16; r++) {
    int rl = (r & 3) + ((r >> 2) << 3) + (q2 << 2);
    int rg = tr + rl;
    if (rg < n) {
      float dv = dinv[rg];
#pragma unroll
      for (int ct = 0; ct < 4; ct++) {
        y[(size_t)rg * FDIM + ct * 32 + m] = f2bf(dv * acc[ct][r]);
      }
    }
  }
}

// ---------------------------------------------------------------------------
// K8: per-node gather (bf16 y rows) + tanh + w_lin dot + bias.
// h[dst] = tanh( dinv[dst] * ( y[dst] + sum_e w_e * y[src_e] ) )
// ---------------------------------------------------------------------------
__global__ __launch_bounds__(256) void gather_kernel(
    const uint32* __restrict__ yb, const int* __restrict__ offs,
    const int2* __restrict__ csr, const float* __restrict__ dinv,
    const float* __restrict__ wl, const float* __restrict__ bl,
    float* __restrict__ out, int n) {
  int wid = (int)((blockIdx.x * (size_t)blockDim.x + threadIdx.x) >> 6);
  int lane = threadIdx.x & 63;
  if (wid >= n) return;
  float di = dinv[wid];
  uint32 uv = yb[(size_t)wid * 64 + lane];
  float ax = __uint_as_float(uv << 16);          // self term, coeff 1
  float ay = __uint_as_float(uv & 0xffff0000u);
  int beg = offs[wid], end = offs[wid + 1];
  int e = beg;
  for (; e + 4 <= end; e += 4) {
    int2 c0 = csr[e];
    int2 c1 = csr[e + 1];
    int2 c2 = csr[e + 2];
    int2 c3 = csr[e + 3];
    uint32 u0 = yb[(size_t)c0.x * 64 + lane];
    uint32 u1 = yb[(size_t)c1.x * 64 + lane];
    uint32 u2 = yb[(size_t)c2.x * 64 + lane];
    uint32 u3 = yb[(size_t)c3.x * 64 + lane];
    float w0 = __int_as_float(c0.y), w1 = __int_as_float(c1.y);
    float w2 = __int_as_float(c2.y), w3 = __int_as_float(c3.y);
    ax += w0 * __uint_as_float(u0 << 16);
    ay += w0 * __uint_as_float(u0 & 0xffff0000u);
    ax += w1 * __uint_as_float(u1 << 16);
    ay += w1 * __uint_as_float(u1 & 0xffff0000u);
    ax += w2 * __uint_as_float(u2 << 16);
    ay += w2 * __uint_as_float(u2 & 0xffff0000u);
    ax += w3 * __uint_as_float(u3 << 16);
    ay += w3 * __uint_as_float(u3 & 0xffff0000u);
  }
  for (; e < end; e++) {
    int2 c = csr[e];
    uint32 u = yb[(size_t)c.x * 64 + lane];
    float wn = __int_as_float(c.y);
    ax += wn * __uint_as_float(u << 16);
    ay += wn * __uint_as_float(u & 0xffff0000u);
  }
  float2 wv = ((const float2*)wl)[lane];
  float p = tanhf(di * ax) * wv.x + tanhf(di * ay) * wv.y;
#pragma unroll
  for (int o = 32; o > 0; o >>= 1) p += __shfl_down(p, o, 64);
  if (lane == 0) out[wid] = p + bl[0];
}

// ---------------------------------------------------------------------------
extern "C" void kernel_launch(void* const* d_in, const int* in_sizes, int n_in,
                              void* d_out, int out_size, void* d_ws,
                              size_t ws_size, hipStream_t stream) {
  const float* x = (const float*)d_in[0];     // (N,128)
  const int* ei = (const int*)d_in[1];        // (2,E)
  const float* ew = (const float*)d_in[2];    // (E,)
  const float* W0 = (const float*)d_in[3];    // (128,128)
  const float* Wih = (const float*)d_in[4];   // (384,128)
  const float* Whh = (const float*)d_in[5];   // (384,128)
  const float* bih = (const float*)d_in[6];   // (384,)
  const float* bhh = (const float*)d_in[7];   // (384,)
  const float* wl = (const float*)d_in[8];    // (1,128)
  const float* bl = (const float*)d_in[9];    // (1,)
  float* out = (float*)d_out;                 // (N,1)

  // Workspace layout (all 16B-aligned)
  float* ws = (float*)d_ws;
  float* W_ev = ws;                                      // 16384 f
  unsigned short* y = (unsigned short*)(W_ev + 16384);   // N*128 bf16
  float* dinv = (float*)(y + (size_t)N_NODES * FDIM);    // 50000 f
  int* cnt = (int*)(dinv + N_NODES);                     // 50000 i
  int* rank = cnt + N_NODES;                             // 800000 i
  int* offs = rank + N_EDGES;                            // 50004 i (padded)
  int2* csr = (int2*)(offs + 50004);                     // 800000 int2
  int* part = (int*)(csr + N_EDGES);                     // 256 i

  // K1: evolve W
  evolve_kernel<<<FDIM, 384, 0, stream>>>(W0, Wih, Whh, bih, bhh, W_ev);
  // K2: zero cnt (async memset is graph-capturable)
  hipMemsetAsync(cnt, 0, sizeof(int) * N_NODES, stream);
  // K3: rank histogram (single atomic per edge)
  hist_kernel<<<(N_EDGES + 255) / 256, 256, 0, stream>>>(ei, cnt, rank,
                                                         N_EDGES);
  // K5a: block partial sums
  partial_kernel<<<SCAN_BLOCKS, 256, 0, stream>>>(cnt, part, N_NODES);
  // K5b: scan partials
  scan_part_kernel<<<1, 256, 0, stream>>>(part);
  // K5c: final scan -> offs
  scan_final_kernel<<<SCAN_BLOCKS, 256, 0, stream>>>(cnt, part, offs, N_NODES);
  // K6: scatter to CSR (no atomics)
  scatter_kernel<<<(N_EDGES + 255) / 256, 256, 0, stream>>>(ei, ew, offs, rank,
                                                            csr, N_EDGES);
  // K6b: deg from CSR -> dinv (atomic-free)
  deg_dinv_kernel<<<(N_NODES + 255) / 256, 256, 0, stream>>>(csr, offs, dinv,
                                                             N_NODES);
  // K7: y = dinv * (x @ W_ev) -> bf16, MFMA  (1563 tiles of 32 rows)
  xw_mfma_kernel<<<391, 256, 0, stream>>>(x, W_ev, dinv, y, N_NODES);
  // K8: fused gather + tanh + linear
  gather_kernel<<<(N_NODES * 64) / 256, 256, 0, stream>>>(
      (const uint32*)y, offs, csr, dinv, wl, bl, out, N_NODES);
}

// Round 6
// 212.349 us; speedup vs baseline: 2.2361x; 1.0088x over previous
//
#include <hip/hip_runtime.h>
#include <hip/hip_bf16.h>
#include <math.h>

#define N_NODES 50000
#define N_EDGES 800000
#define FDIM 128
#define SCAN_BLOCKS 196   // ceil(50000/256)
#define XW_BLOCKS 391     // ceil(50000/128) row-tiles of 32 x 4 waves

typedef unsigned int uint32;
typedef __attribute__((ext_vector_type(8))) __bf16 bf16x8;
typedef __attribute__((ext_vector_type(8))) short short8;
typedef __attribute__((ext_vector_type(16))) float f32x16;

// part[] layout (ints): [0..195] raw block sums, [200] flagA, [201] flagB,
//                       [256..451] scanned (exclusive) block offsets
#define FLAG_A 200
#define FLAG_B 201
#define SCANNED 256

// round-to-nearest-even fp32 -> bf16 bits (finite inputs)
__device__ inline unsigned short f2bf(float f) {
  unsigned int u = __float_as_uint(f);
  unsigned int r = u + 0x7fffu + ((u >> 16) & 1u);
  return (unsigned short)(r >> 16);
}

// ---------------------------------------------------------------------------
// K1: GRU-evolve W (128x128) + zero cnt/flags (fused init).
// ---------------------------------------------------------------------------
__global__ __launch_bounds__(384) void evolve_kernel(
    const float* __restrict__ W0, const float* __restrict__ Wih,
    const float* __restrict__ Whh, const float* __restrict__ bih,
    const float* __restrict__ bhh, float* __restrict__ W,
    int* __restrict__ cnt, int* __restrict__ part) {
  int i = blockIdx.x;       // 0..127
  int jj = threadIdx.x;     // 0..383
  // fused init: zero cnt[0..N_NODES) and the two scan flags
  int gid = i * 384 + jj;   // 0..49151
  for (int j = gid; j < N_NODES; j += 128 * 384) cnt[j] = 0;
  if (gid == 0) part[FLAG_A] = 0;
  if (gid == 1) part[FLAG_B] = 0;

  __shared__ float w0s[FDIM];
  __shared__ float gis[3 * FDIM];
  __shared__ float ghs[3 * FDIM];
  if (jj < FDIM) w0s[jj] = W0[i * FDIM + jj];
  __syncthreads();
  float gi = bih[jj], gh = bhh[jj];
  const float4* wih4 = (const float4*)(Wih + jj * FDIM);
  const float4* whh4 = (const float4*)(Whh + jj * FDIM);
#pragma unroll 8
  for (int k = 0; k < FDIM / 4; k++) {
    float4 a = wih4[k];
    float4 b = whh4[k];
    float w0a = w0s[4 * k], w0b = w0s[4 * k + 1];
    float w0c = w0s[4 * k + 2], w0d = w0s[4 * k + 3];
    gi += a.x * w0a + a.y * w0b + a.z * w0c + a.w * w0d;
    gh += b.x * w0a + b.y * w0b + b.z * w0c + b.w * w0d;
  }
  gis[jj] = gi;
  ghs[jj] = gh;
  __syncthreads();
  if (jj < FDIM) {
    float r = 1.0f / (1.0f + expf(-(gis[jj] + ghs[jj])));
    float z = 1.0f / (1.0f + expf(-(gis[jj + FDIM] + ghs[jj + FDIM])));
    float nn = tanhf(gis[jj + 2 * FDIM] + r * ghs[jj + 2 * FDIM]);
    W[i * FDIM + jj] = (1.0f - z) * nn + z * w0s[jj];
  }
}

// ---------------------------------------------------------------------------
// K2 (fused): blocks [0,XW_BLOCKS) run the MFMA GEMM y = bf16(x @ W);
// blocks [XW_BLOCKS, ...) run the rank histogram (1 atomic/edge).
// xw blocks are FIRST so they launch immediately; hist blocks (atomic-latency
// bound, low pipe use) fill the remaining CUs concurrently.
// ---------------------------------------------------------------------------
__global__ __launch_bounds__(256) void histxw_kernel(
    const int* __restrict__ ei, int* __restrict__ cnt, int* __restrict__ rank,
    const float* __restrict__ x, const float* __restrict__ W,
    unsigned short* __restrict__ y, int n) {
  __shared__ short Bs[16 * 128 * 8];  // 32 KiB (xw path only)
  int t = threadIdx.x;
  if (blockIdx.x >= XW_BLOCKS) {
    // ---- hist path ----
    int idx = (blockIdx.x - XW_BLOCKS) * 256 + t;
    if (idx < N_EDGES) {
      int dst = ei[N_EDGES + idx];
      rank[idx] = atomicAdd(&cnt[dst], 1);
    }
    return;
  }
  // ---- xw path: one wave per 32-row tile, 32x32x16 bf16 MFMA ----
  // stage W -> LDS (bf16, frag-blocked): Bs[kg][n][j] = W[kg*8+j][n]
#pragma unroll
  for (int i = 0; i < 64; i++) {
    int idx = i * 256 + t;  // coalesced read of W[k][n]
    int k = idx >> 7, nn = idx & 127;
    Bs[(((k >> 3) << 7) + nn) * 8 + (k & 7)] = (short)f2bf(W[idx]);
  }
  __syncthreads();

  int lane = t & 63;
  int wid = blockIdx.x * 4 + (t >> 6);
  int tr = wid * 32;  // tile row base
  if (tr >= n) return;
  int m = lane & 31;   // A row / D col within tile
  int q2 = lane >> 5;  // half-wave: k-offset selector

  int row = tr + m;
  if (row >= n) row = n - 1;  // tail clamp (stores are guarded)
  const float* xr = x + (size_t)row * FDIM;

  bf16x8 a[8];
#pragma unroll
  for (int kc = 0; kc < 8; kc++) {
    int k0 = kc * 16 + q2 * 8;
    float4 p = *(const float4*)(xr + k0);
    float4 q = *(const float4*)(xr + k0 + 4);
    short8 s;
    s[0] = (short)f2bf(p.x); s[1] = (short)f2bf(p.y);
    s[2] = (short)f2bf(p.z); s[3] = (short)f2bf(p.w);
    s[4] = (short)f2bf(q.x); s[5] = (short)f2bf(q.y);
    s[6] = (short)f2bf(q.z); s[7] = (short)f2bf(q.w);
    a[kc] = __builtin_bit_cast(bf16x8, s);
  }

  f32x16 acc[4];
#pragma unroll
  for (int ct = 0; ct < 4; ct++) {
#pragma unroll
    for (int r = 0; r < 16; r++) acc[ct][r] = 0.0f;
  }
#pragma unroll
  for (int ct = 0; ct < 4; ct++) {
    int nn = ct * 32 + m;
#pragma unroll
    for (int kc = 0; kc < 8; kc++) {
      int kg = kc * 2 + q2;
      bf16x8 b = __builtin_bit_cast(
          bf16x8, *(const short8*)(Bs + (((kg << 7) + nn) << 3)));
      acc[ct] = __builtin_amdgcn_mfma_f32_32x32x16_bf16(a[kc], b, acc[ct], 0,
                                                        0, 0);
    }
  }

  // D layout: col = lane&31, row = (reg&3) + 8*(reg>>2) + 4*(lane>>5)
#pragma unroll
  for (int r = 0; r < 16; r++) {
    int rl = (r & 3) + ((r >> 2) << 3) + (q2 << 2);
    int rg = tr + rl;
    if (rg < n) {
#pragma unroll
      for (int ct = 0; ct < 4; ct++) {
        y[(size_t)rg * FDIM + ct * 32 + m] = f2bf(acc[ct][r]);
      }
    }
  }
}

// ---------------------------------------------------------------------------
// K3: single-dispatch device-wide exclusive scan of cnt -> offs.
// 196 blocks x 256 (all co-resident on 256 CUs). Release/acquire flags.
// ---------------------------------------------------------------------------
__global__ __launch_bounds__(256) void scan_all_kernel(
    const int* __restrict__ cnt, int* __restrict__ part, int* __restrict__ offs,
    int n) {
  __shared__ int tmp[256];
  int t = threadIdx.x;
  int bid = blockIdx.x;
  int idx = bid * 256 + t;
  int v = (idx < n) ? cnt[idx] : 0;
  tmp[t] = v;
  __syncthreads();
#pragma unroll
  for (int off = 1; off < 256; off <<= 1) {
    int u = (t >= off) ? tmp[t - off] : 0;
    __syncthreads();
    tmp[t] += u;
    __syncthreads();
  }
  int local_excl = tmp[t] - v;
  int block_sum = tmp[255];
  // publish block sum
  if (t == 0) {
    __hip_atomic_store(&part[bid], block_sum, __ATOMIC_RELEASE,
                       __HIP_MEMORY_SCOPE_AGENT);
    __hip_atomic_fetch_add(&part[FLAG_A], 1, __ATOMIC_ACQ_REL,
                           __HIP_MEMORY_SCOPE_AGENT);
  }
  // block 0 scans the partials once all have arrived
  if (bid == 0) {
    if (t == 0) {
      while (__hip_atomic_load(&part[FLAG_A], __ATOMIC_ACQUIRE,
                               __HIP_MEMORY_SCOPE_AGENT) < SCAN_BLOCKS) {
        __builtin_amdgcn_s_sleep(1);
      }
    }
    __syncthreads();
    __shared__ int ps[256];
    int pv = (t < SCAN_BLOCKS)
                 ? __hip_atomic_load(&part[t], __ATOMIC_RELAXED,
                                     __HIP_MEMORY_SCOPE_AGENT)
                 : 0;
    ps[t] = pv;
    __syncthreads();
#pragma unroll
    for (int off = 1; off < 256; off <<= 1) {
      int u = (t >= off) ? ps[t - off] : 0;
      __syncthreads();
      ps[t] += u;
      __syncthreads();
    }
    if (t < SCAN_BLOCKS)
      __hip_atomic_store(&part[SCANNED + t], ps[t] - pv, __ATOMIC_RELAXED,
                         __HIP_MEMORY_SCOPE_AGENT);
    __syncthreads();
    if (t == 0)
      __hip_atomic_store(&part[FLAG_B], 1, __ATOMIC_RELEASE,
                         __HIP_MEMORY_SCOPE_AGENT);
  }
  // all blocks wait for scanned offsets
  if (t == 0) {
    while (__hip_atomic_load(&part[FLAG_B], __ATOMIC_ACQUIRE,
                             __HIP_MEMORY_SCOPE_AGENT) == 0) {
      __builtin_amdgcn_s_sleep(1);
    }
  }
  __syncthreads();
  int base = __hip_atomic_load(&part[SCANNED + bid], __ATOMIC_RELAXED,
                               __HIP_MEMORY_SCOPE_AGENT);
  int excl = base + local_excl;
  if (idx < n) offs[idx] = excl;
  if (idx == n - 1) offs[n] = excl + v;
}

// ---------------------------------------------------------------------------
// K4: scatter edges into CSR-by-dst (no atomics: pos = offs[dst]+rank).
// CSR entry packed as int2{src, raw-edge-weight bits}.
// ---------------------------------------------------------------------------
__global__ void scatter_kernel(const int* __restrict__ ei,
                               const float* __restrict__ ew,
                               const int* __restrict__ offs,
                               const int* __restrict__ rank,
                               int2* __restrict__ csr, int e) {
  int idx = blockIdx.x * blockDim.x + threadIdx.x;
  if (idx < e) {
    int src = ei[idx];
    int dst = ei[N_EDGES + idx];
    int pos = offs[dst] + rank[idx];
    csr[pos] = make_int2(src, __float_as_int(ew[idx]));
  }
}

// ---------------------------------------------------------------------------
// K5: deg from finished CSR (atomic-free) -> dinv. One thread per node.
// ---------------------------------------------------------------------------
__global__ __launch_bounds__(256) void deg_dinv_kernel(
    const int2* __restrict__ csr, const int* __restrict__ offs,
    float* __restrict__ dinv, int n) {
  int i = blockIdx.x * blockDim.x + threadIdx.x;
  if (i >= n) return;
  int b = offs[i], e = offs[i + 1];
  float d = 1.0f;
  for (int j = b; j < e; j++) d += __int_as_float(csr[j].y);
  dinv[i] = (d > 0.0f) ? rsqrtf(d) : 0.0f;
}

// ---------------------------------------------------------------------------
// K6: per-node gather (bf16 y rows) + tanh + w_lin dot + bias.
// h[dst] = tanh( dinv_d * ( dinv_d*y[dst] + sum_e w_e*dinv_src*y[src_e] ) )
// dinv applied per-edge in fp32 (y no longer carries it).
// ---------------------------------------------------------------------------
__global__ __launch_bounds__(256) void gather_kernel(
    const uint32* __restrict__ yb, const int* __restrict__ offs,
    const int2* __restrict__ csr, const float* __restrict__ dinv,
    const float* __restrict__ wl, const float* __restrict__ bl,
    float* __restrict__ out, int n) {
  int wid = (int)((blockIdx.x * (size_t)blockDim.x + threadIdx.x) >> 6);
  int lane = threadIdx.x & 63;
  if (wid >= n) return;
  float di = dinv[wid];
  uint32 uv = yb[(size_t)wid * 64 + lane];
  float ax = di * __uint_as_float(uv << 16);  // self term (one dinv_d here,
  float ay = di * __uint_as_float(uv & 0xffff0000u);  // second applied at end)
  int beg = offs[wid], end = offs[wid + 1];
  int e = beg;
  for (; e + 4 <= end; e += 4) {
    int2 c0 = csr[e];
    int2 c1 = csr[e + 1];
    int2 c2 = csr[e + 2];
    int2 c3 = csr[e + 3];
    uint32 u0 = yb[(size_t)c0.x * 64 + lane];
    uint32 u1 = yb[(size_t)c1.x * 64 + lane];
    uint32 u2 = yb[(size_t)c2.x * 64 + lane];
    uint32 u3 = yb[(size_t)c3.x * 64 + lane];
    float w0 = __int_as_float(c0.y) * dinv[c0.x];
    float w1 = __int_as_float(c1.y) * dinv[c1.x];
    float w2 = __int_as_float(c2.y) * dinv[c2.x];
    float w3 = __int_as_float(c3.y) * dinv[c3.x];
    ax += w0 * __uint_as_float(u0 << 16);
    ay += w0 * __uint_as_float(u0 & 0xffff0000u);
    ax += w1 * __uint_as_float(u1 << 16);
    ay += w1 * __uint_as_float(u1 & 0xffff0000u);
    ax += w2 * __uint_as_float(u2 << 16);
    ay += w2 * __uint_as_float(u2 & 0xffff0000u);
    ax += w3 * __uint_as_float(u3 << 16);
    ay += w3 * __uint_as_float(u3 & 0xffff0000u);
  }
  for (; e < end; e++) {
    int2 c = csr[e];
    uint32 u = yb[(size_t)c.x * 64 + lane];
    float wn = __int_as_float(c.y) * dinv[c.x];
    ax += wn * __uint_as_float(u << 16);
    ay += wn * __uint_as_float(u & 0xffff0000u);
  }
  float2 wv = ((const float2*)wl)[lane];
  float p = tanhf(di * ax) * wv.x + tanhf(di * ay) * wv.y;
#pragma unroll
  for (int o = 32; o > 0; o >>= 1) p += __shfl_down(p, o, 64);
  if (lane == 0) out[wid] = p + bl[0];
}

// ---------------------------------------------------------------------------
extern "C" void kernel_launch(void* const* d_in, const int* in_sizes, int n_in,
                              void* d_out, int out_size, void* d_ws,
                              size_t ws_size, hipStream_t stream) {
  const float* x = (const float*)d_in[0];     // (N,128)
  const int* ei = (const int*)d_in[1];        // (2,E)
  const float* ew = (const float*)d_in[2];    // (E,)
  const float* W0 = (const float*)d_in[3];    // (128,128)
  const float* Wih = (const float*)d_in[4];   // (384,128)
  const float* Whh = (const float*)d_in[5];   // (384,128)
  const float* bih = (const float*)d_in[6];   // (384,)
  const float* bhh = (const float*)d_in[7];   // (384,)
  const float* wl = (const float*)d_in[8];    // (1,128)
  const float* bl = (const float*)d_in[9];    // (1,)
  float* out = (float*)d_out;                 // (N,1)

  // Workspace layout (all 16B-aligned)
  float* ws = (float*)d_ws;
  float* W_ev = ws;                                      // 16384 f
  unsigned short* y = (unsigned short*)(W_ev + 16384);   // N*128 bf16
  float* dinv = (float*)(y + (size_t)N_NODES * FDIM);    // 50000 f
  int* cnt = (int*)(dinv + N_NODES);                     // 50000 i
  int* rank = cnt + N_NODES;                             // 800000 i
  int* offs = rank + N_EDGES;                            // 50004 i (padded)
  int2* csr = (int2*)(offs + 50004);                     // 800000 int2
  int* part = (int*)(csr + N_EDGES);                     // 512 i

  // D1: evolve W + zero cnt/flags
  evolve_kernel<<<FDIM, 384, 0, stream>>>(W0, Wih, Whh, bih, bhh, W_ev, cnt,
                                          part);
  // D2: fused xw-MFMA (blocks 0..390) + rank histogram (blocks 391..)
  histxw_kernel<<<XW_BLOCKS + (N_EDGES + 255) / 256, 256, 0, stream>>>(
      ei, cnt, rank, x, W_ev, y, N_NODES);
  // D3: single-dispatch scan -> offs
  scan_all_kernel<<<SCAN_BLOCKS, 256, 0, stream>>>(cnt, part, offs, N_NODES);
  // D4: scatter to CSR (no atomics)
  scatter_kernel<<<(N_EDGES + 255) / 256, 256, 0, stream>>>(ei, ew, offs, rank,
                                                            csr, N_EDGES);
  // D5: deg from CSR -> dinv (atomic-free)
  deg_dinv_kernel<<<(N_NODES + 255) / 256, 256, 0, stream>>>(csr, offs, dinv,
                                                             N_NODES);
  // D6: fused gather + tanh + linear
  gather_kernel<<<(N_NODES * 64) / 256, 256, 0, stream>>>(
      (const uint32*)y, offs, csr, dinv, wl, bl, out, N_NODES);
}